// Round 2
// baseline (683.817 us; speedup 1.0000x reference)
//
#include <hip/hip_runtime.h>

#define T_DIM 200
#define U_DIM 100
#define D_DIM 512
#define V_DIM 1024
#define TU_DIM (T_DIM * U_DIM)   // 20000
#define M_TOTAL (8 * TU_DIM)     // 160000 rows
#define M_TILE 64
#define N_TILE 128

typedef __attribute__((ext_vector_type(8))) short bf16x8;
typedef __attribute__((ext_vector_type(4))) float f32x4;

__device__ __forceinline__ unsigned short f2bf(float f) {
    unsigned int u = __float_as_uint(f);
    u += 0x7FFFu + ((u >> 16) & 1u);   // RNE to bf16
    return (unsigned short)(u >> 16);
}

__device__ __forceinline__ float fast_tanh(float x) {
    float e = __expf(2.0f * x);
    return 1.0f - 2.0f / (e + 1.0f);
}

// ---- prep: convert joiner_w (V,D) f32 -> bf16 into workspace ----
__global__ void conv_w_kernel(const float* __restrict__ w, ushort4* __restrict__ wbf) {
    int i = blockIdx.x * blockDim.x + threadIdx.x;    // 131072 float4 chunks
    float4 v = reinterpret_cast<const float4*>(w)[i];
    ushort4 o;
    o.x = f2bf(v.x); o.y = f2bf(v.y); o.z = f2bf(v.z); o.w = f2bf(v.w);
    wbf[i] = o;
}

__global__ __launch_bounds__(512, 2)
void joiner_kernel(const float* __restrict__ enc,
                   const int* __restrict__ prefix,
                   const float* __restrict__ emb,
                   const unsigned short* __restrict__ wbf,
                   const float* __restrict__ bias,
                   float* __restrict__ out) {
    // A tile, XOR-swizzled: element addr = row*512 + ((chunk ^ (row&7))*8), chunk = 16B unit
    __shared__ unsigned short A_s[M_TILE * 512];     // 64 KiB, no pad

    const int tid = threadIdx.x;
    const long long g0 = (long long)blockIdx.x * M_TILE;

    // ---------- Phase 1: A = bf16(tanh(enc_row + emb[prefix])), swizzled into LDS ----------
    {
        const int r = tid >> 3;          // 0..63 row
        const int q = tid & 7;
        const int g = (int)g0 + r;
        const int b = g / TU_DIM;
        const int m = g - b * TU_DIM;
        const int t = m / U_DIM;
        const int u = m - t * U_DIM;
        const float* encp = enc + (size_t)(b * T_DIM + t) * D_DIM;
        const float* embp = emb + (size_t)prefix[b * U_DIM + u] * D_DIM;
        const int r7 = r & 7;
#pragma unroll
        for (int jj = 0; jj < 8; ++jj) {
            const int d = q * 8 + jj * 64;       // element offset (chunk = q + 8*jj)
            float4 e0 = *reinterpret_cast<const float4*>(encp + d);
            float4 e1 = *reinterpret_cast<const float4*>(encp + d + 4);
            float4 p0 = *reinterpret_cast<const float4*>(embp + d);
            float4 p1 = *reinterpret_cast<const float4*>(embp + d + 4);
            bf16x8 pk;
            pk[0] = (short)f2bf(fast_tanh(e0.x + p0.x));
            pk[1] = (short)f2bf(fast_tanh(e0.y + p0.y));
            pk[2] = (short)f2bf(fast_tanh(e0.z + p0.z));
            pk[3] = (short)f2bf(fast_tanh(e0.w + p0.w));
            pk[4] = (short)f2bf(fast_tanh(e1.x + p1.x));
            pk[5] = (short)f2bf(fast_tanh(e1.y + p1.y));
            pk[6] = (short)f2bf(fast_tanh(e1.z + p1.z));
            pk[7] = (short)f2bf(fast_tanh(e1.w + p1.w));
            const int chunk = (q + 8 * jj) ^ r7;
            *reinterpret_cast<bf16x8*>(&A_s[r * 512 + chunk * 8]) = pk;
        }
    }
    __syncthreads();   // the ONLY barrier

    // ---------- Phase 2: hoist A fragments to registers (read once) ----------
    const int lane = tid & 63;
    const int wid  = tid >> 6;           // 8 waves: 2 (m) x 4 (n)
    const int wm   = (wid >> 2) * 32;
    const int wn   = (wid & 3) * 32;
    const int lr   = lane & 15;
    const int lg   = lane >> 4;

    bf16x8 a_reg[16][2];                 // 16 k-slices x 2 m-frags = 128 VGPR
#pragma unroll
    for (int s = 0; s < 16; ++s) {
#pragma unroll
        for (int mi = 0; mi < 2; ++mi) {
            const int row = wm + mi * 16 + lr;
            const int chunk = (s * 4 + lg) ^ (row & 7);
            a_reg[s][mi] = *reinterpret_cast<const bf16x8*>(&A_s[row * 512 + chunk * 8]);
        }
    }

    // ---------- Phase 3: barrier-free v-loop, W b-frags straight from L2 ----------
    // b-frag for 16x16x32: col = lane&15 (W row wn+lr), k = lg*8 + slice*32 (+j)
    const unsigned short* wp0 = wbf + (size_t)(wn + lr) * D_DIM + lg * 8;

    for (int vt = 0; vt < 8; ++vt) {
        const int v0 = vt * N_TILE;
        const unsigned short* wp = wp0 + (size_t)v0 * D_DIM;
        f32x4 acc[2][2];
#pragma unroll
        for (int mi = 0; mi < 2; ++mi)
#pragma unroll
            for (int ni = 0; ni < 2; ++ni)
                acc[mi][ni] = (f32x4){0.f, 0.f, 0.f, 0.f};

#pragma unroll
        for (int s = 0; s < 16; ++s) {
            bf16x8 b0 = *reinterpret_cast<const bf16x8*>(wp + s * 32);
            bf16x8 b1 = *reinterpret_cast<const bf16x8*>(wp + 16 * D_DIM + s * 32);
            acc[0][0] = __builtin_amdgcn_mfma_f32_16x16x32_bf16(a_reg[s][0], b0, acc[0][0], 0, 0, 0);
            acc[1][0] = __builtin_amdgcn_mfma_f32_16x16x32_bf16(a_reg[s][1], b0, acc[1][0], 0, 0, 0);
            acc[0][1] = __builtin_amdgcn_mfma_f32_16x16x32_bf16(a_reg[s][0], b1, acc[0][1], 0, 0, 0);
            acc[1][1] = __builtin_amdgcn_mfma_f32_16x16x32_bf16(a_reg[s][1], b1, acc[1][1], 0, 0, 0);
        }

        // epilogue: bias + store (v contiguous per 16-lane group)
        const float bv0 = bias[v0 + wn + lr];
        const float bv1 = bias[v0 + wn + 16 + lr];
#pragma unroll
        for (int mi = 0; mi < 2; ++mi) {
#pragma unroll
            for (int j = 0; j < 4; ++j) {
                const long long row = g0 + wm + mi * 16 + lg * 4 + j;
                float* op = out + row * V_DIM + v0 + wn;
                op[lr]      = acc[mi][0][j] + bv0;
                op[16 + lr] = acc[mi][1][j] + bv1;
            }
        }
    }
}

extern "C" void kernel_launch(void* const* d_in, const int* in_sizes, int n_in,
                              void* d_out, int out_size, void* d_ws, size_t ws_size,
                              hipStream_t stream) {
    const float* enc    = (const float*)d_in[0];   // (8,200,512) f32
    const int*   prefix = (const int*)d_in[1];     // (8,100) int
    const float* emb    = (const float*)d_in[2];   // (1024,512) f32
    const float* jw     = (const float*)d_in[3];   // (1024,512) f32
    const float* jb     = (const float*)d_in[4];   // (1024,) f32
    float* out = (float*)d_out;                    // (8,200,100,1024) f32
    unsigned short* wbf = (unsigned short*)d_ws;   // 1 MB bf16 W

    conv_w_kernel<<<512, 256, 0, stream>>>(jw, (ushort4*)wbf);
    joiner_kernel<<<M_TOTAL / M_TILE, 512, 0, stream>>>(enc, prefix, emb, wbf, jb, out);
}

// Round 3
// 419.683 us; speedup vs baseline: 1.6294x; 1.6294x over previous
//
#include <hip/hip_runtime.h>

#define T_DIM 200
#define U_DIM 100
#define D_DIM 512
#define V_DIM 1024
#define TU_DIM (T_DIM * U_DIM)   // 20000
#define M_TOTAL (8 * TU_DIM)     // 160000 rows
#define M_TILE 64

typedef __attribute__((ext_vector_type(8))) short bf16x8;
typedef __attribute__((ext_vector_type(4))) float f32x4;

__device__ __forceinline__ unsigned short f2bf(float f) {
    unsigned int u = __float_as_uint(f);
    u += 0x7FFFu + ((u >> 16) & 1u);   // RNE to bf16
    return (unsigned short)(u >> 16);
}

__device__ __forceinline__ float fast_tanh(float x) {
    float e = __expf(2.0f * x);
    return 1.0f - 2.0f / (e + 1.0f);
}

// ---- prep: convert joiner_w (V,D) f32 -> bf16 into workspace ----
__global__ void conv_w_kernel(const float* __restrict__ w, ushort4* __restrict__ wbf) {
    int i = blockIdx.x * blockDim.x + threadIdx.x;    // 131072 float4 chunks
    float4 v = reinterpret_cast<const float4*>(w)[i];
    ushort4 o;
    o.x = f2bf(v.x); o.y = f2bf(v.y); o.z = f2bf(v.z); o.w = f2bf(v.w);
    wbf[i] = o;
}

__global__ __launch_bounds__(512, 2)
void joiner_kernel(const float* __restrict__ enc,
                   const int* __restrict__ prefix,
                   const float* __restrict__ emb,
                   const unsigned short* __restrict__ wbf,
                   const float* __restrict__ bias,
                   float* __restrict__ out) {
    // A tile, XOR-swizzled: elem addr = row*512 + ((chunk ^ (row&7))*8), chunk=16B unit
    __shared__ unsigned short A_s[M_TILE * 512];     // 64 KiB

    const int tid = threadIdx.x;
    const long long g0 = (long long)blockIdx.x * M_TILE;

    // ---------- Phase 1: A = bf16(tanh(enc_row + emb[prefix])), swizzled into LDS ----------
    {
        const int r = tid >> 3;          // 0..63 row
        const int q = tid & 7;
        const int g = (int)g0 + r;
        const int b = g / TU_DIM;
        const int m = g - b * TU_DIM;
        const int t = m / U_DIM;
        const int u = m - t * U_DIM;
        const float* encp = enc + (size_t)(b * T_DIM + t) * D_DIM;
        const float* embp = emb + (size_t)prefix[b * U_DIM + u] * D_DIM;
        const int r7 = r & 7;
#pragma unroll
        for (int jj = 0; jj < 8; ++jj) {
            const int d = q * 8 + jj * 64;       // elem offset (chunk = q + 8*jj)
            float4 e0 = *reinterpret_cast<const float4*>(encp + d);
            float4 e1 = *reinterpret_cast<const float4*>(encp + d + 4);
            float4 p0 = *reinterpret_cast<const float4*>(embp + d);
            float4 p1 = *reinterpret_cast<const float4*>(embp + d + 4);
            bf16x8 pk;
            pk[0] = (short)f2bf(fast_tanh(e0.x + p0.x));
            pk[1] = (short)f2bf(fast_tanh(e0.y + p0.y));
            pk[2] = (short)f2bf(fast_tanh(e0.z + p0.z));
            pk[3] = (short)f2bf(fast_tanh(e0.w + p0.w));
            pk[4] = (short)f2bf(fast_tanh(e1.x + p1.x));
            pk[5] = (short)f2bf(fast_tanh(e1.y + p1.y));
            pk[6] = (short)f2bf(fast_tanh(e1.z + p1.z));
            pk[7] = (short)f2bf(fast_tanh(e1.w + p1.w));
            const int chunk = (q + 8 * jj) ^ r7;
            *reinterpret_cast<bf16x8*>(&A_s[r * 512 + chunk * 8]) = pk;
        }
    }
    __syncthreads();   // the ONLY barrier

    // ---------- Phase 2: each wave owns full M=64 x private 128-col strip ----------
    const int lane = tid & 63;
    const int wid  = tid >> 6;           // 8 waves tile V: wave strip = wid*128
    const int wn   = wid * 128;
    const int lr   = lane & 15;
    const int lg   = lane >> 4;

    // b-frag [ni] slice s: W row (wn + ni*16 + lr), k = s*32 + lg*8
    const unsigned short* wbase = wbf + (size_t)(wn + lr) * D_DIM + lg * 8;

    f32x4 acc[4][8];
#pragma unroll
    for (int mi = 0; mi < 4; ++mi)
#pragma unroll
        for (int ni = 0; ni < 8; ++ni)
            acc[mi][ni] = (f32x4){0.f, 0.f, 0.f, 0.f};

    bf16x8 bb[2][8];                     // one-slice-ahead double buffer (static idx)
#pragma unroll
    for (int ni = 0; ni < 8; ++ni)
        bb[0][ni] = *reinterpret_cast<const bf16x8*>(wbase + ni * 16 * D_DIM);

#pragma unroll
    for (int s = 0; s < 16; ++s) {
        const int cur = s & 1, nxt = cur ^ 1;
        if (s < 15) {
#pragma unroll
            for (int ni = 0; ni < 8; ++ni)
                bb[nxt][ni] = *reinterpret_cast<const bf16x8*>(wbase + ni * 16 * D_DIM + (s + 1) * 32);
        }
        bf16x8 af[4];
#pragma unroll
        for (int mi = 0; mi < 4; ++mi) {
            const int row = mi * 16 + lr;
            const int chunk = (s * 4 + lg) ^ (row & 7);
            af[mi] = *reinterpret_cast<const bf16x8*>(&A_s[row * 512 + chunk * 8]);
        }
#pragma unroll
        for (int mi = 0; mi < 4; ++mi)
#pragma unroll
            for (int ni = 0; ni < 8; ++ni)
                acc[mi][ni] = __builtin_amdgcn_mfma_f32_16x16x32_bf16(af[mi], bb[cur][ni], acc[mi][ni], 0, 0, 0);
    }

    // ---------- epilogue: bias + store ----------
    float bv[8];
#pragma unroll
    for (int ni = 0; ni < 8; ++ni)
        bv[ni] = bias[wn + ni * 16 + lr];

#pragma unroll
    for (int mi = 0; mi < 4; ++mi) {
#pragma unroll
        for (int j = 0; j < 4; ++j) {
            const long long row = g0 + mi * 16 + lg * 4 + j;
            float* op = out + row * V_DIM + wn;
#pragma unroll
            for (int ni = 0; ni < 8; ++ni)
                op[ni * 16 + lr] = acc[mi][ni][j] + bv[ni];
        }
    }
}

extern "C" void kernel_launch(void* const* d_in, const int* in_sizes, int n_in,
                              void* d_out, int out_size, void* d_ws, size_t ws_size,
                              hipStream_t stream) {
    const float* enc    = (const float*)d_in[0];   // (8,200,512) f32
    const int*   prefix = (const int*)d_in[1];     // (8,100) int
    const float* emb    = (const float*)d_in[2];   // (1024,512) f32
    const float* jw     = (const float*)d_in[3];   // (1024,512) f32
    const float* jb     = (const float*)d_in[4];   // (1024,) f32
    float* out = (float*)d_out;                    // (8,200,100,1024) f32
    unsigned short* wbf = (unsigned short*)d_ws;   // 1 MB bf16 W

    conv_w_kernel<<<512, 256, 0, stream>>>(jw, (ushort4*)wbf);
    joiner_kernel<<<M_TOTAL / M_TILE, 512, 0, stream>>>(enc, prefix, emb, wbf, jb, out);
}